// Round 2
// baseline (3812.718 us; speedup 1.0000x reference)
//
#include <hip/hip_runtime.h>
#include <math.h>

#define EPS_YAT (1.0f/137.0f)

__device__ __forceinline__ float4 ld4(const float* p) { return *(const float4*)p; }

// ---- column norms of W [K,N] -> wn[N] ----
__global__ void colnorm_kernel(const float* __restrict__ W, float* __restrict__ wn,
                               int K, int N) {
    int n = blockIdx.x * 256 + threadIdx.x;
    if (n >= N) return;
    float s = 0.f;
    for (int k = 0; k < K; ++k) { float w = W[(size_t)k * N + n]; s += w * w; }
    wn[n] = s;
}

// ---- row norms of X [R,K] -> rn[R]; one wave per row, 4 rows/block ----
__global__ void rownorm_kernel(const float* __restrict__ X, float* __restrict__ rn, int K) {
    int wave = threadIdx.x >> 6;
    int lane = threadIdx.x & 63;
    int row = blockIdx.x * 4 + wave;
    const float* xr = X + (size_t)row * K;
    float s = 0.f;
    for (int k = lane * 4; k < K; k += 256) {
        float4 v = ld4(xr + k);
        s += v.x * v.x + v.y * v.y + v.z * v.z + v.w * v.w;
    }
    for (int off = 32; off; off >>= 1) s += __shfl_down(s, off);
    if (lane == 0) rn[row] = s;
}

// ---- q/k norms from qkv [B,T,3C]: qn/kn indexed [b*H+h][t] ----
__global__ void qknorm_kernel(const float* __restrict__ qkv, float* __restrict__ qn,
                              float* __restrict__ kn) {
    int gid = blockIdx.x * 256 + threadIdx.x;
    int lane = gid & 15;
    int idx = gid >> 4;                  // 0..98303
    int which = (idx >= 49152) ? 1 : 0;  // 0=q, 1=k
    int r = idx - which * 49152;
    int t = r & 1023;
    int bh = r >> 10;
    int h = bh % 12, b = bh / 12;
    const float* p = qkv + (size_t)(b * 1024 + t) * 2304 + which * 768 + h * 64 + lane * 4;
    float4 v = ld4(p);
    float s = v.x * v.x + v.y * v.y + v.z * v.z + v.w * v.w;
    s += __shfl_xor(s, 1, 16);
    s += __shfl_xor(s, 2, 16);
    s += __shfl_xor(s, 4, 16);
    s += __shfl_xor(s, 8, 16);
    if (lane == 0) (which ? kn : qn)[r] = s;
}

// ---- yat GEMM: out[m,n] = yat(A[m,:]·W[:,n]); 64x128 tile, 4x8 micro ----
__global__ __launch_bounds__(256)
void yat_gemm_kernel(const float* __restrict__ A, const float* __restrict__ W,
                     const float* __restrict__ bias, const float* __restrict__ xn,
                     const float* __restrict__ wn, const float* __restrict__ alphap,
                     const float Fdim, float* __restrict__ out,
                     const int M, const int N, const int K) {
    __shared__ float As[32][68];   // [k][m], padded
    __shared__ float Bs[32][132];  // [k][n], padded
    const int tid = threadIdx.x;
    const int m0 = blockIdx.y << 6;
    const int n0 = blockIdx.x << 7;
    const int r4 = (tid >> 4) << 2;
    const int c8 = (tid & 15) << 3;
    float acc[4][8] = {};
    const int la_m = tid >> 3;
    const int la_k = (tid & 7) << 2;
    const int lb_r = tid >> 5;
    const int lb_c = (tid & 31) << 2;
    for (int k0 = 0; k0 < K; k0 += 32) {
        __syncthreads();
        #pragma unroll
        for (int l = 0; l < 2; ++l) {
            int m = la_m + (l << 5);
            float4 v = ld4(A + (size_t)(m0 + m) * K + k0 + la_k);
            As[la_k + 0][m] = v.x;
            As[la_k + 1][m] = v.y;
            As[la_k + 2][m] = v.z;
            As[la_k + 3][m] = v.w;
        }
        #pragma unroll
        for (int l = 0; l < 4; ++l) {
            int kk = lb_r + (l << 3);
            *(float4*)&Bs[kk][lb_c] = ld4(W + (size_t)(k0 + kk) * N + n0 + lb_c);
        }
        __syncthreads();
        #pragma unroll
        for (int kk = 0; kk < 32; ++kk) {
            float4 av  = *(const float4*)&As[kk][r4];
            float4 bv0 = *(const float4*)&Bs[kk][c8];
            float4 bv1 = *(const float4*)&Bs[kk][c8 + 4];
            float aa[4] = {av.x, av.y, av.z, av.w};
            float bb[8] = {bv0.x, bv0.y, bv0.z, bv0.w, bv1.x, bv1.y, bv1.z, bv1.w};
            #pragma unroll
            for (int i = 0; i < 4; ++i)
                #pragma unroll
                for (int j = 0; j < 8; ++j)
                    acc[i][j] += aa[i] * bb[j];
        }
    }
    const float scale = powf(sqrtf(Fdim) / log1pf(Fdim), *alphap);
    #pragma unroll
    for (int i = 0; i < 4; ++i) {
        const int m = m0 + r4 + i;
        const float xnm = xn[m];
        float o[8];
        #pragma unroll
        for (int j = 0; j < 8; ++j) {
            const int n = n0 + c8 + j;
            float d = acc[i][j];
            float den = xnm + wn[n] - 2.f * d + EPS_YAT;
            o[j] = (d * d / den + bias[n]) * scale;
        }
        float* op = out + (size_t)m * N + n0 + c8;
        *(float4*)op       = make_float4(o[0], o[1], o[2], o[3]);
        *(float4*)(op + 4) = make_float4(o[4], o[5], o[6], o[7]);
    }
}

// ---- flash attention with yat score; 64 q-rows per block ----
// Padded rows (stride 68 floats): all hot LDS patterns are broadcast or <=2-way
// (free). Ps aliases Ks (dead after S). LDS = 3*64*68*4 + 512 = 52.7 KB ->
// 3 blocks/CU; launch_bounds(256,3) caps VGPR ~170 -> 12 waves/CU.
__global__ __launch_bounds__(256, 3)
void yat_flash_kernel(const float* __restrict__ qkv, const float* __restrict__ qn,
                      const float* __restrict__ kn, float* __restrict__ out) {
    __shared__ float Qs[64 * 68], Ks[64 * 68], Vs[64 * 68];
    __shared__ float qns[64], kns[64];
    float* Ps = Ks;  // alias: Ks dead once S is computed
    const int tid = threadIdx.x;
    // balanced task map: even blocks take heavy tasks (qt 15..8) in descending
    // order, odd blocks take light tasks (qt 7..0) ascending -> adjacent blocks
    // mix heavy+light regardless of dispatcher striding.
    const int L = blockIdx.x;
    const int u = L >> 1;
    const int rnk = (L & 1) ? (767 - u) : u;
    const int qt = 15 - (rnk / 48);
    const int bh = rnk % 48;
    const int h = bh % 12, b = bh / 12;
    const int lr = tid >> 4;
    const int lc = (tid & 15) << 2;
    const size_t base = (size_t)b * 1024 * 2304 + h * 64;
    #pragma unroll
    for (int l = 0; l < 4; ++l) {
        int row = lr + l * 16;
        int t = (qt << 6) + row;
        *(float4*)&Qs[row * 68 + lc] = ld4(qkv + base + (size_t)t * 2304 + lc);
    }
    if (tid < 64) qns[tid] = qn[bh * 1024 + (qt << 6) + tid];
    const int r = tid >> 4, c = tid & 15;
    const int r4 = r << 2, c4 = c << 2;
    float acc[4][4] = {};
    float mrow[4] = {-3e38f, -3e38f, -3e38f, -3e38f};
    float lrow[4] = {0.f, 0.f, 0.f, 0.f};

    for (int kt = 0; kt <= qt; ++kt) {
        __syncthreads();  // prev PV (reads Ps=Ks, Vs) done before overwrite
        #pragma unroll
        for (int l = 0; l < 4; ++l) {
            int row = lr + l * 16;
            int t = (kt << 6) + row;
            *(float4*)&Ks[row * 68 + lc] = ld4(qkv + base + 768  + (size_t)t * 2304 + lc);
            *(float4*)&Vs[row * 68 + lc] = ld4(qkv + base + 1536 + (size_t)t * 2304 + lc);
        }
        if (tid < 64) kns[tid] = kn[bh * 1024 + (kt << 6) + tid];
        __syncthreads();

        // S = Q K^T (4x4 micro over 64-d)
        float s[4][4] = {};
        #pragma unroll
        for (int d = 0; d < 64; d += 4) {
            float4 aR[4], bR[4];
            #pragma unroll
            for (int i = 0; i < 4; ++i) aR[i] = *(const float4*)&Qs[(r4 + i) * 68 + d];
            #pragma unroll
            for (int j = 0; j < 4; ++j) bR[j] = *(const float4*)&Ks[(c4 + j) * 68 + d];
            #pragma unroll
            for (int i = 0; i < 4; ++i)
                #pragma unroll
                for (int j = 0; j < 4; ++j)
                    s[i][j] += aR[i].x * bR[j].x + aR[i].y * bR[j].y +
                               aR[i].z * bR[j].z + aR[i].w * bR[j].w;
        }
        __syncthreads();  // all Ks reads done before P overwrites it

        // yat score + causal mask + online softmax
        float mt[4];
        #pragma unroll
        for (int i = 0; i < 4; ++i) {
            int ig = (qt << 6) + r4 + i;
            float qni = qns[r4 + i];
            float mm = -3e38f;
            #pragma unroll
            for (int j = 0; j < 4; ++j) {
                int jg = (kt << 6) + c4 + j;
                float sv = s[i][j] * 0.125f;
                float num = sv * sv;
                float den = qni + kns[c4 + j] - 2.f * sv + EPS_YAT;
                float sc = (jg <= ig) ? (num / den) : -3e38f;
                s[i][j] = sc;
                mm = fmaxf(mm, sc);
            }
            mt[i] = mm;
        }
        #pragma unroll
        for (int i = 0; i < 4; ++i) {
            float mm = mt[i];
            mm = fmaxf(mm, __shfl_xor(mm, 8, 16));
            mm = fmaxf(mm, __shfl_xor(mm, 4, 16));
            mm = fmaxf(mm, __shfl_xor(mm, 2, 16));
            mm = fmaxf(mm, __shfl_xor(mm, 1, 16));
            mt[i] = mm;
        }
        #pragma unroll
        for (int i = 0; i < 4; ++i) {
            float mnew = fmaxf(mrow[i], mt[i]);
            float al = __expf(mrow[i] - mnew);
            mrow[i] = mnew;
            float rs = 0.f;
            #pragma unroll
            for (int j = 0; j < 4; ++j) {
                float p = __expf(s[i][j] - mnew);  // masked -> exp(-huge) = 0
                s[i][j] = p;
                rs += p;
            }
            rs += __shfl_xor(rs, 8, 16);
            rs += __shfl_xor(rs, 4, 16);
            rs += __shfl_xor(rs, 2, 16);
            rs += __shfl_xor(rs, 1, 16);
            lrow[i] = lrow[i] * al + rs;
            #pragma unroll
            for (int j = 0; j < 4; ++j) acc[i][j] *= al;
            *(float4*)&Ps[(r4 + i) * 68 + c4] = make_float4(s[i][0], s[i][1], s[i][2], s[i][3]);
        }
        __syncthreads();

        // O += P V
        #pragma unroll
        for (int jj = 0; jj < 64; jj += 4) {
            float4 pR[4], vR[4];
            #pragma unroll
            for (int i = 0; i < 4; ++i) pR[i] = *(const float4*)&Ps[(r4 + i) * 68 + jj];
            #pragma unroll
            for (int t2 = 0; t2 < 4; ++t2) vR[t2] = *(const float4*)&Vs[(jj + t2) * 68 + c4];
            #pragma unroll
            for (int i = 0; i < 4; ++i) {
                acc[i][0] += pR[i].x * vR[0].x + pR[i].y * vR[1].x + pR[i].z * vR[2].x + pR[i].w * vR[3].x;
                acc[i][1] += pR[i].x * vR[0].y + pR[i].y * vR[1].y + pR[i].z * vR[2].y + pR[i].w * vR[3].y;
                acc[i][2] += pR[i].x * vR[0].z + pR[i].y * vR[1].z + pR[i].z * vR[2].z + pR[i].w * vR[3].z;
                acc[i][3] += pR[i].x * vR[0].w + pR[i].y * vR[1].w + pR[i].z * vR[2].w + pR[i].w * vR[3].w;
            }
        }
    }
    #pragma unroll
    for (int i = 0; i < 4; ++i) {
        int t = (qt << 6) + r4 + i;
        float inv = 1.f / lrow[i];
        *(float4*)(out + (size_t)(b * 1024 + t) * 768 + h * 64 + c4) =
            make_float4(acc[i][0] * inv, acc[i][1] * inv, acc[i][2] * inv, acc[i][3] * inv);
    }
}

extern "C" void kernel_launch(void* const* d_in, const int* in_sizes, int n_in,
                              void* d_out, int out_size, void* d_ws, size_t ws_size,
                              hipStream_t stream) {
    const float* x          = (const float*)d_in[0];
    // d_in[1] = mask (causal, known structure — unused)
    const float* W_attn     = (const float*)d_in[2];
    const float* b_attn     = (const float*)d_in[3];
    const float* alpha_attn = (const float*)d_in[4];
    const float* W_proj     = (const float*)d_in[5];
    const float* b_proj     = (const float*)d_in[6];
    const float* alpha_proj = (const float*)d_in[7];

    float* ws       = (float*)d_ws;
    float* qkv      = ws;                 // 4*1024*2304 = 9437184
    float* attn_out = ws + 9437184;       // 4*1024*768  = 3145728
    float* xn       = ws + 12582912;      // 4096
    float* an       = ws + 12587008;      // 4096
    float* wn_attn  = ws + 12591104;      // 2304
    float* wn_proj  = ws + 12593408;      // 768
    float* qn       = ws + 12594176;      // 49152
    float* kn       = ws + 12643328;      // 49152  (end: 12692480 floats ~50.8 MB)

    colnorm_kernel<<<9, 256, 0, stream>>>(W_attn, wn_attn, 768, 2304);
    colnorm_kernel<<<3, 256, 0, stream>>>(W_proj, wn_proj, 768, 768);
    rownorm_kernel<<<1024, 256, 0, stream>>>(x, xn, 768);
    yat_gemm_kernel<<<dim3(18, 64), 256, 0, stream>>>(
        x, W_attn, b_attn, xn, wn_attn, alpha_attn, 2304.f, qkv, 4096, 2304, 768);
    qknorm_kernel<<<6144, 256, 0, stream>>>(qkv, qn, kn);
    yat_flash_kernel<<<768, 256, 0, stream>>>(qkv, qn, kn, attn_out);
    rownorm_kernel<<<1024, 256, 0, stream>>>(attn_out, an, 768);
    yat_gemm_kernel<<<dim3(6, 64), 256, 0, stream>>>(
        attn_out, W_proj, b_proj, an, wn_proj, alpha_proj, 768.f, (float*)d_out, 4096, 768, 768);
}

// Round 3
// 3719.077 us; speedup vs baseline: 1.0252x; 1.0252x over previous
//
#include <hip/hip_runtime.h>
#include <math.h>

#define EPS_YAT (1.0f/137.0f)

__device__ __forceinline__ float4 ld4(const float* p) { return *(const float4*)p; }

// Swizzled 64x64 tile, float4-slot XOR (row>>2): conflict-free for
// (a) same-row broadcast reads, (b) rows strided by 4 at fixed col,
// (c) contiguous row writes. No padding -> 16 KB/tile, b128-aligned.
__device__ __forceinline__ float4* T4(float* t, int row, int s4) {
    return (float4*)(t + row * 64 + ((s4 ^ (row >> 2)) & 15) * 4);
}
__device__ __forceinline__ const float4* T4c(const float* t, int row, int s4) {
    return (const float4*)(t + row * 64 + ((s4 ^ (row >> 2)) & 15) * 4);
}

// ---- column norms of W [K,N] -> wn[N] ----
__global__ void colnorm_kernel(const float* __restrict__ W, float* __restrict__ wn,
                               int K, int N) {
    int n = blockIdx.x * 256 + threadIdx.x;
    if (n >= N) return;
    float s = 0.f;
    for (int k = 0; k < K; ++k) { float w = W[(size_t)k * N + n]; s += w * w; }
    wn[n] = s;
}

// ---- row norms of X [R,K] -> rn[R]; one wave per row, 4 rows/block ----
__global__ void rownorm_kernel(const float* __restrict__ X, float* __restrict__ rn, int K) {
    int wave = threadIdx.x >> 6;
    int lane = threadIdx.x & 63;
    int row = blockIdx.x * 4 + wave;
    const float* xr = X + (size_t)row * K;
    float s = 0.f;
    for (int k = lane * 4; k < K; k += 256) {
        float4 v = ld4(xr + k);
        s += v.x * v.x + v.y * v.y + v.z * v.z + v.w * v.w;
    }
    for (int off = 32; off; off >>= 1) s += __shfl_down(s, off);
    if (lane == 0) rn[row] = s;
}

// ---- q/k norms from qkv [B,T,3C]: qn/kn indexed [b*H+h][t] ----
__global__ void qknorm_kernel(const float* __restrict__ qkv, float* __restrict__ qn,
                              float* __restrict__ kn) {
    int gid = blockIdx.x * 256 + threadIdx.x;
    int lane = gid & 15;
    int idx = gid >> 4;                  // 0..98303
    int which = (idx >= 49152) ? 1 : 0;  // 0=q, 1=k
    int r = idx - which * 49152;
    int t = r & 1023;
    int bh = r >> 10;
    int h = bh % 12, b = bh / 12;
    const float* p = qkv + (size_t)(b * 1024 + t) * 2304 + which * 768 + h * 64 + lane * 4;
    float4 v = ld4(p);
    float s = v.x * v.x + v.y * v.y + v.z * v.z + v.w * v.w;
    s += __shfl_xor(s, 1, 16);
    s += __shfl_xor(s, 2, 16);
    s += __shfl_xor(s, 4, 16);
    s += __shfl_xor(s, 8, 16);
    if (lane == 0) (which ? kn : qn)[r] = s;
}

// ---- yat GEMM: out[m,n] = yat(A[m,:]·W[:,n]); 64x128 tile, 4x8 micro ----
__global__ __launch_bounds__(256)
void yat_gemm_kernel(const float* __restrict__ A, const float* __restrict__ W,
                     const float* __restrict__ bias, const float* __restrict__ xn,
                     const float* __restrict__ wn, const float* __restrict__ alphap,
                     const float Fdim, float* __restrict__ out,
                     const int M, const int N, const int K) {
    __shared__ float As[32][68];   // [k][m], padded
    __shared__ float Bs[32][132];  // [k][n], padded
    const int tid = threadIdx.x;
    const int m0 = blockIdx.y << 6;
    const int n0 = blockIdx.x << 7;
    const int r4 = (tid >> 4) << 2;
    const int c8 = (tid & 15) << 3;
    float acc[4][8] = {};
    const int la_m = tid >> 3;
    const int la_k = (tid & 7) << 2;
    const int lb_r = tid >> 5;
    const int lb_c = (tid & 31) << 2;
    for (int k0 = 0; k0 < K; k0 += 32) {
        __syncthreads();
        #pragma unroll
        for (int l = 0; l < 2; ++l) {
            int m = la_m + (l << 5);
            float4 v = ld4(A + (size_t)(m0 + m) * K + k0 + la_k);
            As[la_k + 0][m] = v.x;
            As[la_k + 1][m] = v.y;
            As[la_k + 2][m] = v.z;
            As[la_k + 3][m] = v.w;
        }
        #pragma unroll
        for (int l = 0; l < 4; ++l) {
            int kk = lb_r + (l << 3);
            *(float4*)&Bs[kk][lb_c] = ld4(W + (size_t)(k0 + kk) * N + n0 + lb_c);
        }
        __syncthreads();
        #pragma unroll
        for (int kk = 0; kk < 32; ++kk) {
            float4 av  = *(const float4*)&As[kk][r4];
            float4 bv0 = *(const float4*)&Bs[kk][c8];
            float4 bv1 = *(const float4*)&Bs[kk][c8 + 4];
            float aa[4] = {av.x, av.y, av.z, av.w};
            float bb[8] = {bv0.x, bv0.y, bv0.z, bv0.w, bv1.x, bv1.y, bv1.z, bv1.w};
            #pragma unroll
            for (int i = 0; i < 4; ++i)
                #pragma unroll
                for (int j = 0; j < 8; ++j)
                    acc[i][j] += aa[i] * bb[j];
        }
    }
    const float scale = powf(sqrtf(Fdim) / log1pf(Fdim), *alphap);
    #pragma unroll
    for (int i = 0; i < 4; ++i) {
        const int m = m0 + r4 + i;
        const float xnm = xn[m];
        float o[8];
        #pragma unroll
        for (int j = 0; j < 8; ++j) {
            const int n = n0 + c8 + j;
            float d = acc[i][j];
            float den = xnm + wn[n] - 2.f * d + EPS_YAT;
            o[j] = (d * d / den + bias[n]) * scale;
        }
        float* op = out + (size_t)m * N + n0 + c8;
        *(float4*)op       = make_float4(o[0], o[1], o[2], o[3]);
        *(float4*)(op + 4) = make_float4(o[4], o[5], o[6], o[7]);
    }
}

// ======================= flash attention (yat score) ========================
// Pairing: block handles q-tiles {pj, 15-pj} of one (b,h) -> constant 17
// score-tile applications per block (perfect balance) and K/V loaded ONCE for
// both. Grid (8,48) x-fastest: consecutive blocks share the K/V stream (L2).

__device__ __forceinline__ void sgemm_qk(const float* Q, const float* K,
                                         int r4, int c4, float s[4][4]) {
    #pragma unroll
    for (int i = 0; i < 4; ++i)
        #pragma unroll
        for (int j = 0; j < 4; ++j) s[i][j] = 0.f;
    const int cslot = c4 >> 2;
    const int rslot0 = r4 >> 2;
    #pragma unroll
    for (int d4 = 0; d4 < 16; ++d4) {
        float4 aR[4], bR[4];
        #pragma unroll
        for (int i = 0; i < 4; ++i) aR[i] = *(const float4*)(Q + (r4 + i) * 64 + ((d4 ^ rslot0) & 15) * 4);
        #pragma unroll
        for (int j = 0; j < 4; ++j) bR[j] = *(const float4*)(K + (c4 + j) * 64 + ((d4 ^ cslot) & 15) * 4);
        #pragma unroll
        for (int i = 0; i < 4; ++i)
            #pragma unroll
            for (int j = 0; j < 4; ++j)
                s[i][j] += aR[i].x * bR[j].x + aR[i].y * bR[j].y +
                           aR[i].z * bR[j].z + aR[i].w * bR[j].w;
    }
}

__device__ __forceinline__ void yat_softmax_store(float s[4][4], const float* qns_,
        const float* kns_, float* Ps, int r4, int c4, bool diag,
        float mrow[4], float lrow[4], float acc[4][4]) {
    #pragma unroll
    for (int i = 0; i < 4; ++i) {
        const float qni = qns_[r4 + i];
        float sc[4];
        float mm = -3e38f;
        #pragma unroll
        for (int j = 0; j < 4; ++j) {
            float sv = s[i][j] * 0.125f;
            float den = qni + kns_[c4 + j] - 2.f * sv + EPS_YAT;
            float v = sv * sv / den;
            if (diag && (c4 + j > r4 + i)) v = -3e38f;
            sc[j] = v;
            mm = fmaxf(mm, v);
        }
        mm = fmaxf(mm, __shfl_xor(mm, 8, 16));
        mm = fmaxf(mm, __shfl_xor(mm, 4, 16));
        mm = fmaxf(mm, __shfl_xor(mm, 2, 16));
        mm = fmaxf(mm, __shfl_xor(mm, 1, 16));
        const float mnew = fmaxf(mrow[i], mm);
        const float al = __expf(mrow[i] - mnew);
        mrow[i] = mnew;
        float rs = 0.f;
        #pragma unroll
        for (int j = 0; j < 4; ++j) {
            float p = __expf(sc[j] - mnew);  // masked -> 0
            sc[j] = p;
            rs += p;
        }
        rs += __shfl_xor(rs, 8, 16);
        rs += __shfl_xor(rs, 4, 16);
        rs += __shfl_xor(rs, 2, 16);
        rs += __shfl_xor(rs, 1, 16);
        lrow[i] = lrow[i] * al + rs;
        #pragma unroll
        for (int j = 0; j < 4; ++j) acc[i][j] *= al;
        *T4(Ps, r4 + i, c4 >> 2) = make_float4(sc[0], sc[1], sc[2], sc[3]);
    }
}

__device__ __forceinline__ void pv_accum(const float* Ps, const float* Vs,
                                         int r4, int c4, float acc[4][4]) {
    const int rslot0 = r4 >> 2;
    const int cslot = c4 >> 2;
    #pragma unroll
    for (int j4 = 0; j4 < 16; ++j4) {
        float4 pR[4], vR[4];
        #pragma unroll
        for (int i = 0; i < 4; ++i) pR[i] = *(const float4*)(Ps + (r4 + i) * 64 + ((j4 ^ rslot0) & 15) * 4);
        #pragma unroll
        for (int t2 = 0; t2 < 4; ++t2) vR[t2] = *(const float4*)(Vs + (j4 * 4 + t2) * 64 + ((cslot ^ j4) & 15) * 4);
        #pragma unroll
        for (int i = 0; i < 4; ++i) {
            acc[i][0] += pR[i].x * vR[0].x + pR[i].y * vR[1].x + pR[i].z * vR[2].x + pR[i].w * vR[3].x;
            acc[i][1] += pR[i].x * vR[0].y + pR[i].y * vR[1].y + pR[i].z * vR[2].y + pR[i].w * vR[3].y;
            acc[i][2] += pR[i].x * vR[0].z + pR[i].y * vR[1].z + pR[i].z * vR[2].z + pR[i].w * vR[3].z;
            acc[i][3] += pR[i].x * vR[0].w + pR[i].y * vR[1].w + pR[i].z * vR[2].w + pR[i].w * vR[3].w;
        }
    }
}

__global__ __launch_bounds__(256, 2)
void yat_flash_kernel(const float* __restrict__ qkv, const float* __restrict__ qn,
                      const float* __restrict__ kn, float* __restrict__ out) {
    __shared__ __align__(16) float Qa[64 * 64], Qb[64 * 64], Ks[64 * 64], Vs[64 * 64];
    __shared__ float qna[64], qnb[64], kns[64];
    float* Ps = Ks;  // Ks dead once both S tiles are computed
    const int tid = threadIdx.x;
    const int pj = blockIdx.x;       // 0..7
    const int bh = blockIdx.y;       // 0..47
    const int qtA = pj;              // light q-tile: kt 0..pj
    const int qtB = 15 - pj;         // heavy q-tile: kt 0..15-pj
    const int h = bh % 12, b = bh / 12;
    const int lr = tid >> 4;         // 0..15
    const int lsl = tid & 15;        // float4 slot 0..15
    const int lc = lsl << 2;
    const size_t base = (size_t)b * 1024 * 2304 + h * 64;
    #pragma unroll
    for (int l = 0; l < 4; ++l) {
        int row = lr + l * 16;
        *T4(Qa, row, lsl) = ld4(qkv + base + (size_t)((qtA << 6) + row) * 2304 + lc);
        *T4(Qb, row, lsl) = ld4(qkv + base + (size_t)((qtB << 6) + row) * 2304 + lc);
    }
    if (tid < 64) qna[tid] = qn[bh * 1024 + (qtA << 6) + tid];
    else if (tid < 128) qnb[tid - 64] = qn[bh * 1024 + (qtB << 6) + (tid - 64)];
    const int r = tid >> 4, c = tid & 15;
    const int r4 = r << 2, c4 = c << 2;
    float accA[4][4] = {}, accB[4][4] = {};
    float mA[4] = {-3e38f, -3e38f, -3e38f, -3e38f};
    float mB[4] = {-3e38f, -3e38f, -3e38f, -3e38f};
    float lAr[4] = {}, lBr[4] = {};

    for (int kt = 0; kt <= qtB; ++kt) {
        __syncthreads();  // prior PV reads (Ps=Ks, Vs) complete before reload
        #pragma unroll
        for (int l = 0; l < 4; ++l) {
            int row = lr + l * 16;
            size_t rb = base + (size_t)((kt << 6) + row) * 2304;
            *T4(Ks, row, lsl) = ld4(qkv + rb + 768 + lc);
            *T4(Vs, row, lsl) = ld4(qkv + rb + 1536 + lc);
        }
        if (tid < 64) kns[tid] = kn[bh * 1024 + (kt << 6) + tid];
        __syncthreads();

        float sB[4][4];
        sgemm_qk(Qb, Ks, r4, c4, sB);
        const bool doA = (kt <= qtA);
        float sA[4][4];
        if (doA) sgemm_qk(Qa, Ks, r4, c4, sA);
        __syncthreads();  // Ks reads done; Ps may overwrite

        yat_softmax_store(sB, qnb, kns, Ps, r4, c4, kt == qtB, mB, lBr, accB);
        __syncthreads();
        pv_accum(Ps, Vs, r4, c4, accB);
        if (doA) {  // block-uniform branch
            __syncthreads();  // P_B reads done
            yat_softmax_store(sA, qna, kns, Ps, r4, c4, kt == qtA, mA, lAr, accA);
            __syncthreads();
            pv_accum(Ps, Vs, r4, c4, accA);
        }
    }
    #pragma unroll
    for (int i = 0; i < 4; ++i) {
        float invB = 1.f / lBr[i];
        *(float4*)(out + (size_t)(b * 1024 + (qtB << 6) + r4 + i) * 768 + h * 64 + c4) =
            make_float4(accB[i][0] * invB, accB[i][1] * invB, accB[i][2] * invB, accB[i][3] * invB);
        float invA = 1.f / lAr[i];
        *(float4*)(out + (size_t)(b * 1024 + (qtA << 6) + r4 + i) * 768 + h * 64 + c4) =
            make_float4(accA[i][0] * invA, accA[i][1] * invA, accA[i][2] * invA, accA[i][3] * invA);
    }
}

extern "C" void kernel_launch(void* const* d_in, const int* in_sizes, int n_in,
                              void* d_out, int out_size, void* d_ws, size_t ws_size,
                              hipStream_t stream) {
    const float* x          = (const float*)d_in[0];
    // d_in[1] = mask (causal, known structure — unused)
    const float* W_attn     = (const float*)d_in[2];
    const float* b_attn     = (const float*)d_in[3];
    const float* alpha_attn = (const float*)d_in[4];
    const float* W_proj     = (const float*)d_in[5];
    const float* b_proj     = (const float*)d_in[6];
    const float* alpha_proj = (const float*)d_in[7];

    float* ws       = (float*)d_ws;
    float* qkv      = ws;                 // 4*1024*2304 = 9437184
    float* attn_out = ws + 9437184;       // 4*1024*768  = 3145728
    float* xn       = ws + 12582912;      // 4096
    float* an       = ws + 12587008;      // 4096
    float* wn_attn  = ws + 12591104;      // 2304
    float* wn_proj  = ws + 12593408;      // 768
    float* qn       = ws + 12594176;      // 49152
    float* kn       = ws + 12643328;      // 49152  (end: 12692480 floats ~50.8 MB)

    colnorm_kernel<<<9, 256, 0, stream>>>(W_attn, wn_attn, 768, 2304);
    colnorm_kernel<<<3, 256, 0, stream>>>(W_proj, wn_proj, 768, 768);
    rownorm_kernel<<<1024, 256, 0, stream>>>(x, xn, 768);
    yat_gemm_kernel<<<dim3(18, 64), 256, 0, stream>>>(
        x, W_attn, b_attn, xn, wn_attn, alpha_attn, 2304.f, qkv, 4096, 2304, 768);
    qknorm_kernel<<<6144, 256, 0, stream>>>(qkv, qn, kn);
    yat_flash_kernel<<<dim3(8, 48), 256, 0, stream>>>(qkv, qn, kn, attn_out);
    rownorm_kernel<<<1024, 256, 0, stream>>>(attn_out, an, 768);
    yat_gemm_kernel<<<dim3(6, 64), 256, 0, stream>>>(
        attn_out, W_proj, b_proj, an, wn_proj, alpha_proj, 768.f, (float*)d_out, 4096, 768, 768);
}

// Round 4
// 2502.096 us; speedup vs baseline: 1.5238x; 1.4864x over previous
//
#include <hip/hip_runtime.h>
#include <math.h>

#define EPS_YAT (1.0f/137.0f)

__device__ __forceinline__ float4 ld4(const float* p) { return *(const float4*)p; }

// Swizzled 64x64 tile, float4-slot XOR (row>>2): conflict-free for
// (a) same-row broadcast reads, (b) rows strided by 4 at fixed slot,
// (c) contiguous row writes. 16 KB/tile, b128-aligned. (0 conflicts in R3.)
__device__ __forceinline__ float4* T4(float* t, int row, int s4) {
    return (float4*)(t + row * 64 + ((s4 ^ (row >> 2)) & 15) * 4);
}

// ---- column norms of W [K,N] -> wn[N] ----
__global__ void colnorm_kernel(const float* __restrict__ W, float* __restrict__ wn,
                               int K, int N) {
    int n = blockIdx.x * 256 + threadIdx.x;
    if (n >= N) return;
    float s = 0.f;
    for (int k = 0; k < K; ++k) { float w = W[(size_t)k * N + n]; s += w * w; }
    wn[n] = s;
}

// ---- row norms of X [R,K] -> rn[R]; one wave per row, 4 rows/block ----
__global__ void rownorm_kernel(const float* __restrict__ X, float* __restrict__ rn, int K) {
    int wave = threadIdx.x >> 6;
    int lane = threadIdx.x & 63;
    int row = blockIdx.x * 4 + wave;
    const float* xr = X + (size_t)row * K;
    float s = 0.f;
    for (int k = lane * 4; k < K; k += 256) {
        float4 v = ld4(xr + k);
        s += v.x * v.x + v.y * v.y + v.z * v.z + v.w * v.w;
    }
    for (int off = 32; off; off >>= 1) s += __shfl_down(s, off);
    if (lane == 0) rn[row] = s;
}

// ---- q/k norms from qkv [B,T,3C]: qn/kn indexed [b*H+h][t] ----
__global__ void qknorm_kernel(const float* __restrict__ qkv, float* __restrict__ qn,
                              float* __restrict__ kn) {
    int gid = blockIdx.x * 256 + threadIdx.x;
    int lane = gid & 15;
    int idx = gid >> 4;                  // 0..98303
    int which = (idx >= 49152) ? 1 : 0;  // 0=q, 1=k
    int r = idx - which * 49152;
    int t = r & 1023;
    int bh = r >> 10;
    int h = bh % 12, b = bh / 12;
    const float* p = qkv + (size_t)(b * 1024 + t) * 2304 + which * 768 + h * 64 + lane * 4;
    float4 v = ld4(p);
    float s = v.x * v.x + v.y * v.y + v.z * v.z + v.w * v.w;
    s += __shfl_xor(s, 1, 16);
    s += __shfl_xor(s, 2, 16);
    s += __shfl_xor(s, 4, 16);
    s += __shfl_xor(s, 8, 16);
    if (lane == 0) (which ? kn : qn)[r] = s;
}

// ---- yat GEMM: out[m,n] = yat(A[m,:]·W[:,n]); 64x128 tile, 4x8 micro ----
__global__ __launch_bounds__(256)
void yat_gemm_kernel(const float* __restrict__ A, const float* __restrict__ W,
                     const float* __restrict__ bias, const float* __restrict__ xn,
                     const float* __restrict__ wn, const float* __restrict__ alphap,
                     const float Fdim, float* __restrict__ out,
                     const int M, const int N, const int K) {
    __shared__ float As[32][68];   // [k][m], padded
    __shared__ float Bs[32][132];  // [k][n], padded
    const int tid = threadIdx.x;
    const int m0 = blockIdx.y << 6;
    const int n0 = blockIdx.x << 7;
    const int r4 = (tid >> 4) << 2;
    const int c8 = (tid & 15) << 3;
    float acc[4][8] = {};
    const int la_m = tid >> 3;
    const int la_k = (tid & 7) << 2;
    const int lb_r = tid >> 5;
    const int lb_c = (tid & 31) << 2;
    for (int k0 = 0; k0 < K; k0 += 32) {
        __syncthreads();
        #pragma unroll
        for (int l = 0; l < 2; ++l) {
            int m = la_m + (l << 5);
            float4 v = ld4(A + (size_t)(m0 + m) * K + k0 + la_k);
            As[la_k + 0][m] = v.x;
            As[la_k + 1][m] = v.y;
            As[la_k + 2][m] = v.z;
            As[la_k + 3][m] = v.w;
        }
        #pragma unroll
        for (int l = 0; l < 4; ++l) {
            int kk = lb_r + (l << 3);
            *(float4*)&Bs[kk][lb_c] = ld4(W + (size_t)(k0 + kk) * N + n0 + lb_c);
        }
        __syncthreads();
        #pragma unroll
        for (int kk = 0; kk < 32; ++kk) {
            float4 av  = *(const float4*)&As[kk][r4];
            float4 bv0 = *(const float4*)&Bs[kk][c8];
            float4 bv1 = *(const float4*)&Bs[kk][c8 + 4];
            float aa[4] = {av.x, av.y, av.z, av.w};
            float bb[8] = {bv0.x, bv0.y, bv0.z, bv0.w, bv1.x, bv1.y, bv1.z, bv1.w};
            #pragma unroll
            for (int i = 0; i < 4; ++i)
                #pragma unroll
                for (int j = 0; j < 8; ++j)
                    acc[i][j] += aa[i] * bb[j];
        }
    }
    const float scale = powf(sqrtf(Fdim) / log1pf(Fdim), *alphap);
    #pragma unroll
    for (int i = 0; i < 4; ++i) {
        const int m = m0 + r4 + i;
        const float xnm = xn[m];
        float o[8];
        #pragma unroll
        for (int j = 0; j < 8; ++j) {
            const int n = n0 + c8 + j;
            float d = acc[i][j];
            float den = xnm + wn[n] - 2.f * d + EPS_YAT;
            o[j] = (d * d / den + bias[n]) * scale;
        }
        float* op = out + (size_t)m * N + n0 + c8;
        *(float4*)op       = make_float4(o[0], o[1], o[2], o[3]);
        *(float4*)(op + 4) = make_float4(o[4], o[5], o[6], o[7]);
    }
}

// ======================= flash attention (yat score) ========================
// Monolithic, one 64-row q-tile per block. Per-thread state kept small
// (acc[4][4]+s[4][4]+m[4]+l[4] ~ 40 floats) so nothing spills to scratch
// (R1-R3 all showed GB-scale scratch WRITE_SIZE). launch_bounds(256,3):
// VGPR cap 170 >> demand, 3 waves/SIMD. LDS = Q,K,V (P aliases K) = 48.5 KB
// -> 3 blocks/CU -> all 768 blocks co-resident. LPT order: qt descending.
__global__ __launch_bounds__(256, 3)
void yat_flash_kernel(const float* __restrict__ qkv, const float* __restrict__ qn,
                      const float* __restrict__ kn, float* __restrict__ out) {
    __shared__ __align__(16) float Qs[4096], Ks[4096], Vs[4096];
    __shared__ float qns[64], kns[64];
    float* Ps = Ks;  // Ks dead once S is computed
    const int tid = threadIdx.x;
    const int L = blockIdx.x;        // 0..767
    const int qt = 15 - (L / 48);    // heavy blocks first (LPT)
    const int bh = L % 48;
    const int h = bh % 12, b = bh / 12;
    const int lr = tid >> 4;         // 0..15
    const int lsl = tid & 15;        // float4 slot
    const int lc = lsl << 2;
    const size_t base = (size_t)b * 2359296 + h * 64;  // b*1024*2304

    #pragma unroll
    for (int l = 0; l < 4; ++l) {
        int row = lr + l * 16;
        *T4(Qs, row, lsl) = ld4(qkv + base + (size_t)((qt << 6) + row) * 2304 + lc);
    }
    if (tid < 64) qns[tid] = qn[bh * 1024 + (qt << 6) + tid];

    const int r4 = lr << 2;          // 0..60
    const int c4 = lc;               // 0..60
    const int rs0 = lr;              // row-group slot base
    const int cs0 = lsl;             // col-group slot base
    float acc[4][4] = {};
    float mrow[4] = {-3e38f, -3e38f, -3e38f, -3e38f};
    float lrow[4] = {0.f, 0.f, 0.f, 0.f};

    for (int kt = 0; kt <= qt; ++kt) {
        __syncthreads();  // prior PV reads (Ps=Ks, Vs) done before reload
        #pragma unroll
        for (int l = 0; l < 4; ++l) {
            int row = lr + l * 16;
            size_t rb = base + (size_t)((kt << 6) + row) * 2304;
            *T4(Ks, row, lsl) = ld4(qkv + rb + 768 + lc);
            *T4(Vs, row, lsl) = ld4(qkv + rb + 1536 + lc);
        }
        if (tid < 64) kns[tid] = kn[bh * 1024 + (kt << 6) + tid];
        __syncthreads();

        // ---- S = Q K^T ----
        float s[4][4] = {};
        #pragma unroll
        for (int d4 = 0; d4 < 16; ++d4) {
            float4 aR[4], bR[4];
            #pragma unroll
            for (int i = 0; i < 4; ++i)
                aR[i] = *(const float4*)(Qs + (r4 + i) * 64 + ((d4 ^ rs0) & 15) * 4);
            #pragma unroll
            for (int j = 0; j < 4; ++j)
                bR[j] = *(const float4*)(Ks + (c4 + j) * 64 + ((d4 ^ cs0) & 15) * 4);
            #pragma unroll
            for (int i = 0; i < 4; ++i)
                #pragma unroll
                for (int j = 0; j < 4; ++j)
                    s[i][j] += aR[i].x * bR[j].x + aR[i].y * bR[j].y +
                               aR[i].z * bR[j].z + aR[i].w * bR[j].w;
        }
        __syncthreads();  // Ks reads done; Ps may overwrite

        // ---- yat score + causal mask + online softmax; P -> LDS ----
        const bool diag = (kt == qt);
        #pragma unroll
        for (int i = 0; i < 4; ++i) {
            const float qni = qns[r4 + i];
            float mm = -3e38f;
            #pragma unroll
            for (int j = 0; j < 4; ++j) {
                float sv = s[i][j] * 0.125f;
                float den = qni + kns[c4 + j] - 2.f * sv + EPS_YAT;
                float v = sv * sv / den;
                if (diag && (c4 + j > r4 + i)) v = -3e38f;
                s[i][j] = v;
                mm = fmaxf(mm, v);
            }
            mm = fmaxf(mm, __shfl_xor(mm, 8, 16));
            mm = fmaxf(mm, __shfl_xor(mm, 4, 16));
            mm = fmaxf(mm, __shfl_xor(mm, 2, 16));
            mm = fmaxf(mm, __shfl_xor(mm, 1, 16));
            const float mnew = fmaxf(mrow[i], mm);
            const float al = __expf(mrow[i] - mnew);
            mrow[i] = mnew;
            float rs = 0.f;
            #pragma unroll
            for (int j = 0; j < 4; ++j) {
                float p = __expf(s[i][j] - mnew);  // masked -> 0
                s[i][j] = p;
                rs += p;
            }
            rs += __shfl_xor(rs, 8, 16);
            rs += __shfl_xor(rs, 4, 16);
            rs += __shfl_xor(rs, 2, 16);
            rs += __shfl_xor(rs, 1, 16);
            lrow[i] = lrow[i] * al + rs;
            acc[i][0] *= al; acc[i][1] *= al; acc[i][2] *= al; acc[i][3] *= al;
            *T4(Ps, r4 + i, lsl) = make_float4(s[i][0], s[i][1], s[i][2], s[i][3]);
        }
        __syncthreads();

        // ---- O += P V ----
        #pragma unroll
        for (int j4 = 0; j4 < 16; ++j4) {
            float4 pR[4], vR[4];
            #pragma unroll
            for (int i = 0; i < 4; ++i)
                pR[i] = *(const float4*)(Ps + (r4 + i) * 64 + ((j4 ^ rs0) & 15) * 4);
            #pragma unroll
            for (int t2 = 0; t2 < 4; ++t2)
                vR[t2] = *(const float4*)(Vs + ((j4 << 2) + t2) * 64 + ((cs0 ^ j4) & 15) * 4);
            #pragma unroll
            for (int i = 0; i < 4; ++i) {
                acc[i][0] += pR[i].x * vR[0].x + pR[i].y * vR[1].x + pR[i].z * vR[2].x + pR[i].w * vR[3].x;
                acc[i][1] += pR[i].x * vR[0].y + pR[i].y * vR[1].y + pR[i].z * vR[2].y + pR[i].w * vR[3].y;
                acc[i][2] += pR[i].x * vR[0].z + pR[i].y * vR[1].z + pR[i].z * vR[2].z + pR[i].w * vR[3].z;
                acc[i][3] += pR[i].x * vR[0].w + pR[i].y * vR[1].w + pR[i].z * vR[2].w + pR[i].w * vR[3].w;
            }
        }
    }

    #pragma unroll
    for (int i = 0; i < 4; ++i) {
        float inv = 1.f / lrow[i];
        *(float4*)(out + (size_t)(b * 1024 + (qt << 6) + r4 + i) * 768 + h * 64 + c4) =
            make_float4(acc[i][0] * inv, acc[i][1] * inv, acc[i][2] * inv, acc[i][3] * inv);
    }
}

extern "C" void kernel_launch(void* const* d_in, const int* in_sizes, int n_in,
                              void* d_out, int out_size, void* d_ws, size_t ws_size,
                              hipStream_t stream) {
    const float* x          = (const float*)d_in[0];
    // d_in[1] = mask (causal, known structure — unused)
    const float* W_attn     = (const float*)d_in[2];
    const float* b_attn     = (const float*)d_in[3];
    const float* alpha_attn = (const float*)d_in[4];
    const float* W_proj     = (const float*)d_in[5];
    const float* b_proj     = (const float*)d_in[6];
    const float* alpha_proj = (const float*)d_in[7];

    float* ws       = (float*)d_ws;
    float* qkv      = ws;                 // 4*1024*2304 = 9437184
    float* attn_out = ws + 9437184;       // 4*1024*768  = 3145728
    float* xn       = ws + 12582912;      // 4096
    float* an       = ws + 12587008;      // 4096
    float* wn_attn  = ws + 12591104;      // 2304
    float* wn_proj  = ws + 12593408;      // 768
    float* qn       = ws + 12594176;      // 49152
    float* kn       = ws + 12643328;      // 49152  (end: 12692480 floats ~50.8 MB)

    colnorm_kernel<<<9, 256, 0, stream>>>(W_attn, wn_attn, 768, 2304);
    colnorm_kernel<<<3, 256, 0, stream>>>(W_proj, wn_proj, 768, 768);
    rownorm_kernel<<<1024, 256, 0, stream>>>(x, xn, 768);
    yat_gemm_kernel<<<dim3(18, 64), 256, 0, stream>>>(
        x, W_attn, b_attn, xn, wn_attn, alpha_attn, 2304.f, qkv, 4096, 2304, 768);
    qknorm_kernel<<<6144, 256, 0, stream>>>(qkv, qn, kn);
    yat_flash_kernel<<<768, 256, 0, stream>>>(qkv, qn, kn, attn_out);
    rownorm_kernel<<<1024, 256, 0, stream>>>(attn_out, an, 768);
    yat_gemm_kernel<<<dim3(6, 64), 256, 0, stream>>>(
        attn_out, W_proj, b_proj, an, wn_proj, alpha_proj, 768.f, (float*)d_out, 4096, 768, 768);
}

// Round 5
// 1145.768 us; speedup vs baseline: 3.3277x; 2.1838x over previous
//
#include <hip/hip_runtime.h>
#include <math.h>

#define EPS_YAT (1.0f/137.0f)

__device__ __forceinline__ float4 ld4(const float* p) { return *(const float4*)p; }

// Swizzled 64x64 tile, float4-slot XOR (row>>2): conflict-free for
// (a) same-row broadcast reads, (b) rows strided by 4 at fixed slot,
// (c) contiguous row writes. 16 KB/tile. (0 conflicts measured R3/R4.)
__device__ __forceinline__ float4* T4(float* t, int row, int s4) {
    return (float4*)(t + row * 64 + ((s4 ^ (row >> 2)) & 15) * 4);
}

// ---- column norms of W [K,N] -> wn[N]; 64 cols/block, 4 k-slices ----
__global__ void colnorm_kernel(const float* __restrict__ W, float* __restrict__ wn,
                               int K, int N) {
    __shared__ float sm[256];
    const int col = blockIdx.x * 64 + (threadIdx.x & 63);
    const int slc = threadIdx.x >> 6;           // 0..3
    const int kper = K >> 2;
    float s = 0.f;
    if (col < N) {
        for (int k = slc * kper; k < (slc + 1) * kper; ++k) {
            float w = W[(size_t)k * N + col];
            s += w * w;
        }
    }
    sm[threadIdx.x] = s;
    __syncthreads();
    if (threadIdx.x < 64 && col < N)
        wn[col] = sm[threadIdx.x] + sm[threadIdx.x + 64] + sm[threadIdx.x + 128] + sm[threadIdx.x + 192];
}

// ---- row norms of X [R,K] -> rn[R]; one wave per row, 4 rows/block ----
__global__ void rownorm_kernel(const float* __restrict__ X, float* __restrict__ rn, int K) {
    int wave = threadIdx.x >> 6;
    int lane = threadIdx.x & 63;
    int row = blockIdx.x * 4 + wave;
    const float* xr = X + (size_t)row * K;
    float s = 0.f;
    for (int k = lane * 4; k < K; k += 256) {
        float4 v = ld4(xr + k);
        s += v.x * v.x + v.y * v.y + v.z * v.z + v.w * v.w;
    }
    for (int off = 32; off; off >>= 1) s += __shfl_down(s, off);
    if (lane == 0) rn[row] = s;
}

// ---- q/k norms from qkv [B,T,3C]: qn/kn indexed [b*H+h][t] ----
__global__ void qknorm_kernel(const float* __restrict__ qkv, float* __restrict__ qn,
                              float* __restrict__ kn) {
    int gid = blockIdx.x * 256 + threadIdx.x;
    int lane = gid & 15;
    int idx = gid >> 4;                  // 0..98303
    int which = (idx >= 49152) ? 1 : 0;  // 0=q, 1=k
    int r = idx - which * 49152;
    int t = r & 1023;
    int bh = r >> 10;
    int h = bh % 12, b = bh / 12;
    const float* p = qkv + (size_t)(b * 1024 + t) * 2304 + which * 768 + h * 64 + lane * 4;
    float4 v = ld4(p);
    float s = v.x * v.x + v.y * v.y + v.z * v.z + v.w * v.w;
    s += __shfl_xor(s, 1, 16);
    s += __shfl_xor(s, 2, 16);
    s += __shfl_xor(s, 4, 16);
    s += __shfl_xor(s, 8, 16);
    if (lane == 0) (which ? kn : qn)[r] = s;
}

// ---- yat GEMM: 64x128 tile, 4x8 micro, reg-prefetch pipelined k-loop ----
__global__ __launch_bounds__(256, 3)
void yat_gemm_kernel(const float* __restrict__ A, const float* __restrict__ W,
                     const float* __restrict__ bias, const float* __restrict__ xn,
                     const float* __restrict__ wn, const float* __restrict__ alphap,
                     const float Fdim, float* __restrict__ out,
                     const int M, const int N, const int K) {
    __shared__ float As[32][68];   // [k][m], padded
    __shared__ float Bs[32][132];  // [k][n], padded
    const int tid = threadIdx.x;
    const int m0 = blockIdx.y << 6;
    const int n0 = blockIdx.x << 7;
    const int r4 = (tid >> 4) << 2;
    const int c8 = (tid & 15) << 3;
    float acc[4][8] = {};
    const int la_m = tid >> 3;
    const int la_k = (tid & 7) << 2;
    const int lb_r = tid >> 5;
    const int lb_c = (tid & 31) << 2;

    // prologue: stage tile k0=0 into registers
    float4 aS0 = ld4(A + (size_t)(m0 + la_m) * K + la_k);
    float4 aS1 = ld4(A + (size_t)(m0 + la_m + 32) * K + la_k);
    float4 bS[4];
    #pragma unroll
    for (int l = 0; l < 4; ++l)
        bS[l] = ld4(W + (size_t)(lb_r + (l << 3)) * N + n0 + lb_c);

    for (int k0 = 0; k0 < K; k0 += 32) {
        __syncthreads();  // prev compute done with LDS
        As[la_k + 0][la_m] = aS0.x; As[la_k + 1][la_m] = aS0.y;
        As[la_k + 2][la_m] = aS0.z; As[la_k + 3][la_m] = aS0.w;
        As[la_k + 0][la_m + 32] = aS1.x; As[la_k + 1][la_m + 32] = aS1.y;
        As[la_k + 2][la_m + 32] = aS1.z; As[la_k + 3][la_m + 32] = aS1.w;
        #pragma unroll
        for (int l = 0; l < 4; ++l)
            *(float4*)&Bs[lb_r + (l << 3)][lb_c] = bS[l];
        __syncthreads();

        if (k0 + 32 < K) {  // prefetch next tile; waits land before next ds_write
            aS0 = ld4(A + (size_t)(m0 + la_m) * K + k0 + 32 + la_k);
            aS1 = ld4(A + (size_t)(m0 + la_m + 32) * K + k0 + 32 + la_k);
            #pragma unroll
            for (int l = 0; l < 4; ++l)
                bS[l] = ld4(W + (size_t)(k0 + 32 + lb_r + (l << 3)) * N + n0 + lb_c);
        }

        #pragma unroll
        for (int kk = 0; kk < 32; ++kk) {
            float4 av  = *(const float4*)&As[kk][r4];
            float4 bv0 = *(const float4*)&Bs[kk][c8];
            float4 bv1 = *(const float4*)&Bs[kk][c8 + 4];
            float aa[4] = {av.x, av.y, av.z, av.w};
            float bb[8] = {bv0.x, bv0.y, bv0.z, bv0.w, bv1.x, bv1.y, bv1.z, bv1.w};
            #pragma unroll
            for (int i = 0; i < 4; ++i)
                #pragma unroll
                for (int j = 0; j < 8; ++j)
                    acc[i][j] += aa[i] * bb[j];
        }
    }
    const float scale = powf(sqrtf(Fdim) / log1pf(Fdim), *alphap);
    #pragma unroll
    for (int i = 0; i < 4; ++i) {
        const int m = m0 + r4 + i;
        const float xnm = xn[m];
        float o[8];
        #pragma unroll
        for (int j = 0; j < 8; ++j) {
            const int n = n0 + c8 + j;
            float d = acc[i][j];
            float den = xnm + wn[n] - 2.f * d + EPS_YAT;
            o[j] = (d * d / den + bias[n]) * scale;
        }
        float* op = out + (size_t)m * N + n0 + c8;
        *(float4*)op       = make_float4(o[0], o[1], o[2], o[3]);
        *(float4*)(op + 4) = make_float4(o[4], o[5], o[6], o[7]);
    }
}

// ======================= flash attention (yat score) ========================
// Monolithic 64-row q-tile per block, K/V global->reg prefetch pipelined one
// iteration ahead (loads overlap the full QK+softmax+PV phase instead of
// stalling at vmcnt(0)+barrier each iter — R4 showed VALUBusy 7.3%,
// latency-bound). LDS = Q,K,V (P aliases K) = 48.5 KB -> 3 blocks/CU.
__global__ __launch_bounds__(256, 3)
void yat_flash_kernel(const float* __restrict__ qkv, const float* __restrict__ qn,
                      const float* __restrict__ kn, float* __restrict__ out) {
    __shared__ __align__(16) float Qs[4096], Ks[4096], Vs[4096];
    __shared__ float kns[64];
    float* Ps = Ks;  // Ks dead once S is computed
    const int tid = threadIdx.x;
    const int L = blockIdx.x;        // 0..767
    // interleaved qt table: balances per-CU work under stride-256 block
    // triples while keeping bh = L%48 (same-bh -> same L%8 -> XCD locality)
    const int qt_tab[16] = {15,0,14,1,13,2,12,3,11,4,10,5,9,6,8,7};
    const int qt = qt_tab[L / 48];
    const int bh = L % 48;
    const int h = bh % 12, b = bh / 12;
    const int lr = tid >> 4;         // 0..15
    const int lsl = tid & 15;        // float4 slot
    const int lc = lsl << 2;
    const size_t base = (size_t)b * 2359296 + h * 64;  // b*1024*2304

    #pragma unroll
    for (int l = 0; l < 4; ++l) {
        int row = lr + l * 16;
        *T4(Qs, row, lsl) = ld4(qkv + base + (size_t)((qt << 6) + row) * 2304 + lc);
    }

    const int r4 = lr << 2;          // 0..60
    const int c4 = lc;               // 0..60
    const int rs0 = lr;
    const int cs0 = lsl;
    float qnr[4];
    #pragma unroll
    for (int i = 0; i < 4; ++i) qnr[i] = qn[bh * 1024 + (qt << 6) + r4 + i];

    float acc[4][4] = {};
    float mrow[4] = {-3e38f, -3e38f, -3e38f, -3e38f};
    float lrow[4] = {0.f, 0.f, 0.f, 0.f};

    // stage kt=0 K/V into registers
    float4 kS[4], vS[4];
    #pragma unroll
    for (int l = 0; l < 4; ++l) {
        size_t rb = base + (size_t)(lr + l * 16) * 2304;
        kS[l] = ld4(qkv + rb + 768 + lc);
        vS[l] = ld4(qkv + rb + 1536 + lc);
    }
    float knS = (tid < 64) ? kn[bh * 1024 + tid] : 0.f;

    for (int kt = 0; kt <= qt; ++kt) {
        __syncthreads();  // prior PV reads (Ps=Ks, Vs) done before overwrite
        #pragma unroll
        for (int l = 0; l < 4; ++l) {
            int row = lr + l * 16;
            *T4(Ks, row, lsl) = kS[l];
            *T4(Vs, row, lsl) = vS[l];
        }
        if (tid < 64) kns[tid] = knS;
        __syncthreads();

        if (kt < qt) {  // prefetch kt+1 (block-uniform); ~full phase of slack
            #pragma unroll
            for (int l = 0; l < 4; ++l) {
                size_t rb = base + (size_t)(((kt + 1) << 6) + lr + l * 16) * 2304;
                kS[l] = ld4(qkv + rb + 768 + lc);
                vS[l] = ld4(qkv + rb + 1536 + lc);
            }
            if (tid < 64) knS = kn[bh * 1024 + ((kt + 1) << 6) + tid];
        }

        // ---- S = Q K^T ----
        float s[4][4] = {};
        #pragma unroll
        for (int d4 = 0; d4 < 16; ++d4) {
            float4 aR[4], bR[4];
            #pragma unroll
            for (int i = 0; i < 4; ++i)
                aR[i] = *(const float4*)(Qs + (r4 + i) * 64 + ((d4 ^ rs0) & 15) * 4);
            #pragma unroll
            for (int j = 0; j < 4; ++j)
                bR[j] = *(const float4*)(Ks + (c4 + j) * 64 + ((d4 ^ cs0) & 15) * 4);
            #pragma unroll
            for (int i = 0; i < 4; ++i)
                #pragma unroll
                for (int j = 0; j < 4; ++j)
                    s[i][j] += aR[i].x * bR[j].x + aR[i].y * bR[j].y +
                               aR[i].z * bR[j].z + aR[i].w * bR[j].w;
        }
        __syncthreads();  // Ks reads done; Ps may overwrite

        // ---- yat score + causal mask + online softmax; P -> LDS ----
        const bool diag = (kt == qt);
        #pragma unroll
        for (int i = 0; i < 4; ++i) {
            float mm = -3e38f;
            #pragma unroll
            for (int j = 0; j < 4; ++j) {
                float sv = s[i][j] * 0.125f;
                float den = qnr[i] + kns[c4 + j] - 2.f * sv + EPS_YAT;
                float v = sv * sv / den;
                if (diag && (c4 + j > r4 + i)) v = -3e38f;
                s[i][j] = v;
                mm = fmaxf(mm, v);
            }
            mm = fmaxf(mm, __shfl_xor(mm, 8, 16));
            mm = fmaxf(mm, __shfl_xor(mm, 4, 16));
            mm = fmaxf(mm, __shfl_xor(mm, 2, 16));
            mm = fmaxf(mm, __shfl_xor(mm, 1, 16));
            const float mnew = fmaxf(mrow[i], mm);
            const float al = __expf(mrow[i] - mnew);
            mrow[i] = mnew;
            float rs = 0.f;
            #pragma unroll
            for (int j = 0; j < 4; ++j) {
                float p = __expf(s[i][j] - mnew);  // masked -> 0
                s[i][j] = p;
                rs += p;
            }
            rs += __shfl_xor(rs, 8, 16);
            rs += __shfl_xor(rs, 4, 16);
            rs += __shfl_xor(rs, 2, 16);
            rs += __shfl_xor(rs, 1, 16);
            lrow[i] = lrow[i] * al + rs;
            acc[i][0] *= al; acc[i][1] *= al; acc[i][2] *= al; acc[i][3] *= al;
            *T4(Ps, r4 + i, lsl) = make_float4(s[i][0], s[i][1], s[i][2], s[i][3]);
        }
        __syncthreads();

        // ---- O += P V ----
        #pragma unroll
        for (int j4 = 0; j4 < 16; ++j4) {
            float4 pR[4], vR[4];
            #pragma unroll
            for (int i = 0; i < 4; ++i)
                pR[i] = *(const float4*)(Ps + (r4 + i) * 64 + ((j4 ^ rs0) & 15) * 4);
            #pragma unroll
            for (int t2 = 0; t2 < 4; ++t2)
                vR[t2] = *(const float4*)(Vs + ((j4 << 2) + t2) * 64 + ((cs0 ^ j4) & 15) * 4);
            #pragma unroll
            for (int i = 0; i < 4; ++i) {
                acc[i][0] += pR[i].x * vR[0].x + pR[i].y * vR[1].x + pR[i].z * vR[2].x + pR[i].w * vR[3].x;
                acc[i][1] += pR[i].x * vR[0].y + pR[i].y * vR[1].y + pR[i].z * vR[2].y + pR[i].w * vR[3].y;
                acc[i][2] += pR[i].x * vR[0].z + pR[i].y * vR[1].z + pR[i].z * vR[2].z + pR[i].w * vR[3].z;
                acc[i][3] += pR[i].x * vR[0].w + pR[i].y * vR[1].w + pR[i].z * vR[2].w + pR[i].w * vR[3].w;
            }
        }
    }

    #pragma unroll
    for (int i = 0; i < 4; ++i) {
        float inv = 1.f / lrow[i];
        *(float4*)(out + (size_t)(b * 1024 + (qt << 6) + r4 + i) * 768 + h * 64 + c4) =
            make_float4(acc[i][0] * inv, acc[i][1] * inv, acc[i][2] * inv, acc[i][3] * inv);
    }
}

extern "C" void kernel_launch(void* const* d_in, const int* in_sizes, int n_in,
                              void* d_out, int out_size, void* d_ws, size_t ws_size,
                              hipStream_t stream) {
    const float* x          = (const float*)d_in[0];
    // d_in[1] = mask (causal, known structure — unused)
    const float* W_attn     = (const float*)d_in[2];
    const float* b_attn     = (const float*)d_in[3];
    const float* alpha_attn = (const float*)d_in[4];
    const float* W_proj     = (const float*)d_in[5];
    const float* b_proj     = (const float*)d_in[6];
    const float* alpha_proj = (const float*)d_in[7];

    float* ws       = (float*)d_ws;
    float* qkv      = ws;                 // 4*1024*2304 = 9437184
    float* attn_out = ws + 9437184;       // 4*1024*768  = 3145728
    float* xn       = ws + 12582912;      // 4096
    float* an       = ws + 12587008;      // 4096
    float* wn_attn  = ws + 12591104;      // 2304
    float* wn_proj  = ws + 12593408;      // 768
    float* qn       = ws + 12594176;      // 49152
    float* kn       = ws + 12643328;      // 49152  (end: 12692480 floats ~50.8 MB)

    colnorm_kernel<<<36, 256, 0, stream>>>(W_attn, wn_attn, 768, 2304);
    colnorm_kernel<<<12, 256, 0, stream>>>(W_proj, wn_proj, 768, 768);
    rownorm_kernel<<<1024, 256, 0, stream>>>(x, xn, 768);
    yat_gemm_kernel<<<dim3(18, 64), 256, 0, stream>>>(
        x, W_attn, b_attn, xn, wn_attn, alpha_attn, 2304.f, qkv, 4096, 2304, 768);
    qknorm_kernel<<<6144, 256, 0, stream>>>(qkv, qn, kn);
    yat_flash_kernel<<<768, 256, 0, stream>>>(qkv, qn, kn, attn_out);
    rownorm_kernel<<<1024, 256, 0, stream>>>(attn_out, an, 768);
    yat_gemm_kernel<<<dim3(6, 64), 256, 0, stream>>>(
        attn_out, W_proj, b_proj, an, wn_proj, alpha_proj, 768.f, (float*)d_out, 4096, 768, 768);
}